// Round 10
// baseline (1282.924 us; speedup 1.0000x reference)
//
#include <hip/hip_runtime.h>
#include <math.h>
#include <stdint.h>

// Problem constants
#define B_   256
#define T_   128
#define NIN_ 1024
#define H1_  512
#define E_   256
#define A_   16
#define MT_  (B_ * T_)   // 32768 rows, t-major: m = t*B_ + b

typedef unsigned short ushort_t;
typedef unsigned long long ull_t;
typedef __attribute__((ext_vector_type(8))) short   short8;
typedef __attribute__((ext_vector_type(8))) __bf16  bf16x8;
typedef __attribute__((ext_vector_type(4))) float   f32x4;

union frag8 { short8 s; bf16x8 b; };

__device__ __forceinline__ ushort_t f2bf(float f) {
  union { float f; unsigned u; } v; v.f = f;
  unsigned r = (v.u + 0x7FFFu + ((v.u >> 16) & 1u)) >> 16;   // RNE
  return (ushort_t)r;
}

// ---------------- workspace layout (bytes) ----------------
// C0 fp32 [T*B][1024] = 128MB at 0 (written late; obs_b bf16 64MB overlays it early)
// chunks of C0 row: [0:256)=Penc(h_enc init) [256:512)=r_pre0 [512:768)=z_pre0 [768:1024)=hn0
static constexpr size_t OFF_C0    = 0;
static constexpr size_t OFF_OBSB  = 0;                      // bf16 [32768][1024], dead after G1
static constexpr size_t OFF_Y     = 134217728;              // fp32 [32768][512] (Y1,Y2)
static constexpr size_t OFF_YG    = 134217728;              // fp32 [32768][256] (after Y2 dead)
static constexpr size_t OFF_XG    = 167772160;              // bf16 [32768][256]
static constexpr size_t OFF_PENCB = 184549376;              // bf16 [32768][256] (after BN2)
static constexpr size_t OFF_XB    = 201326592;              // bf16 [32768][512] (X1,X2)
static constexpr size_t OFF_INN   = 201326592;              // fp32 [32768][256] (after XB dead)
static constexpr size_t OFF_AE    = 234881024;              // fp32 [32768][16]
static constexpr size_t OFF_W1T   = 236978176;              // bf16 [512][1024]
static constexpr size_t OFF_W2T   = 238026752;              // bf16 [512][512]
static constexpr size_t OFF_W3T   = 238551040;              // bf16 [256][512]
static constexpr size_t OFF_WIHT  = 239075328;              // bf16 [768][256]
static constexpr size_t OFF_WHHT  = 239468544;              // bf16 [768][256]
static constexpr size_t OFF_WCT   = 240123904;              // bf16 [1024][256]  (combined W^T)
static constexpr size_t OFF_BSUM  = 241172480;              // fp32 [768]
static constexpr size_t OFF_FLAGS = 241176576;              // u32 [16] spaced 128B
static constexpr size_t OFF_HG    = 241238016;              // u64 [2][256][64] (bf16x4 h slices)

// ---------------- prologue kernels ----------------

// obs [B,T,NIN] fp32 -> obs_b bf16 t-major [t*B+b][NIN]
__global__ __launch_bounds__(256) void cast_obs_k(const float* __restrict__ obs,
                                                  ushort_t* __restrict__ out) {
  int row_in = blockIdx.x;              // b*T + t
  int b = row_in / T_, t = row_in - b * T_;
  const float4* s4 = (const float4*)(obs + (size_t)row_in * NIN_);
  float4 v = s4[threadIdx.x];
  ushort_t* d = out + (size_t)(t * B_ + b) * NIN_ + threadIdx.x * 4;
  d[0] = f2bf(v.x); d[1] = f2bf(v.y); d[2] = f2bf(v.z); d[3] = f2bf(v.w);
}

// generic fp32 [R,C] -> bf16 [C,R] transpose+cast
__global__ __launch_bounds__(256) void transpose_cast_k(const float* __restrict__ in,
                                                        ushort_t* __restrict__ out,
                                                        int R, int C) {
  __shared__ float tile[32][33];
  int c0 = blockIdx.x * 32, r0 = blockIdx.y * 32;
  int tx = threadIdx.x & 31, ty = threadIdx.x >> 5;   // ty 0..7
  for (int i = 0; i < 4; i++) {
    int r = r0 + ty * 4 + i;
    if (r < R && (c0 + tx) < C) tile[ty * 4 + i][tx] = in[(size_t)r * C + c0 + tx];
  }
  __syncthreads();
  for (int i = 0; i < 4; i++) {
    int c = c0 + ty * 4 + i, r = r0 + tx;
    if (c < C && r < R) out[(size_t)c * R + r] = f2bf(tile[tx][ty * 4 + i]);
  }
}

// Wct rows 0..255: (Whe_h)^T  : Wct[c][k] = Whe[k][c]
__global__ __launch_bounds__(256) void wct_a_k(const float* __restrict__ Whe,
                                               ushort_t* __restrict__ Wct) {
  int c = blockIdx.x, k = threadIdx.x;
  Wct[(size_t)c * 256 + k] = f2bf(Whe[(size_t)k * 256 + c]);
}

// Wct rows 256..1023: (Whe_h @ Whh)^T computed in fp32, one bf16 rounding
__global__ __launch_bounds__(256) void wct_b_k(const float* __restrict__ Whe,
                                               const float* __restrict__ Whh,
                                               ushort_t* __restrict__ Wct) {
  int c = blockIdx.x;   // 0..767 (gh column)
  int k = threadIdx.x;  // h feature
  float acc = 0.f;
  for (int j = 0; j < 256; j++)
    acc += Whe[(size_t)k * 256 + j] * Whh[(size_t)j * 768 + c];
  Wct[(size_t)(256 + c) * 256 + k] = f2bf(acc);
}

__global__ void bsum_k(const float* __restrict__ bih, const float* __restrict__ bhh,
                       float* __restrict__ bs) {
  int i = blockIdx.x * 256 + threadIdx.x;
  if (i < 768) bs[i] = bih[i] + bhh[i];
}

__global__ void init_flags_k(unsigned* f) {
  if (threadIdx.x < 16) f[threadIdx.x * 32] = 0u;
}

// AE[m=t*B+b][k2] = actions[b,t,:] @ Wae + bae   (fp32)
__global__ __launch_bounds__(256) void ae_k(const float* __restrict__ actions,
                                            const float* __restrict__ Wae,
                                            const float* __restrict__ bae,
                                            float* __restrict__ AE) {
  int idx = blockIdx.x * 256 + threadIdx.x;
  int m = idx >> 4, k2 = idx & 15;
  int t = m >> 8, b = m & 255;
  const float* arow = actions + ((size_t)b * T_ + t) * A_;
  float acc = bae[k2];
  for (int k = 0; k < 16; k++) acc += arow[k] * Wae[k * 16 + k2];
  AE[(size_t)m * 16 + k2] = acc;
}

// Penc[t][b][j] = bhe[j] + (t>0 ? AE[t-1,b,:] @ Whe[256:272,:] : 0)
// writes fp32 into C0 cols [0:256) and bf16 copy to Pencb
__global__ __launch_bounds__(256) void penc_k(const float* __restrict__ AE,
                                              const float* __restrict__ Whe,
                                              const float* __restrict__ bhe,
                                              float* __restrict__ C0,
                                              ushort_t* __restrict__ Pencb) {
  int m = blockIdx.x;          // t*B + b
  int j = threadIdx.x;         // 0..255
  __shared__ float a[16];
  if (threadIdx.x < 16)
    a[threadIdx.x] = (m >= B_) ? AE[(size_t)(m - B_) * 16 + threadIdx.x] : 0.f;
  __syncthreads();
  float acc = bhe[j];
  if (m >= B_) {
    for (int k = 0; k < 16; k++) acc += a[k] * Whe[(size_t)(256 + k) * 256 + j];
  }
  C0[(size_t)m * 1024 + j] = acc;
  Pencb[(size_t)m * 256 + j] = f2bf(acc);
}

// per-t BatchNorm (training, biased var) + ELU, fp32 in -> bf16 out
// per-feature stats are column-independent -> split features across blockIdx.y
__global__ __launch_bounds__(256) void bn_elu_k(const float* __restrict__ Y,
                                                const float* __restrict__ g,
                                                const float* __restrict__ be,
                                                ushort_t* __restrict__ Xb) {
  int t = blockIdx.x, f = blockIdx.y * 256 + threadIdx.x;   // 512 features over 2 blocks
  const float* base = Y + (size_t)t * B_ * H1_;
  float s = 0.f, ss = 0.f;
  for (int b = 0; b < B_; b++) {
    float v = base[(size_t)b * H1_ + f];
    s += v; ss += v * v;
  }
  float mu  = s * (1.f / B_);
  float var = ss * (1.f / B_) - mu * mu;
  float inv = 1.f / sqrtf(var + 1e-5f);
  float sc = g[f] * inv, sh = be[f] - mu * sc;
  ushort_t* ob = Xb + (size_t)t * B_ * H1_;
  for (int b = 0; b < B_; b++) {
    float v = base[(size_t)b * H1_ + f] * sc + sh;
    float e = v > 0.f ? v : (expf(v) - 1.f);
    ob[(size_t)b * H1_ + f] = f2bf(e);
  }
}

__global__ __launch_bounds__(256) void cast_k(const float* __restrict__ in,
                                              ushort_t* __restrict__ out, long n) {
  long i = (long)blockIdx.x * 256 + threadIdx.x;
  if (i < n) out[i] = f2bf(in[i]);
}

// ---------------- bf16 MFMA GEMM: C[m,n] (+)= A[m,:] . Bt[n,:] + bias[n] ----------------
// 128x128 tile, BK=32, 256 threads (4 waves in 2x2, each 64x64, 4x4 frag grid).
__global__ __launch_bounds__(256) void gemm_bt_k(const ushort_t* __restrict__ A, int lda,
                                                 const ushort_t* __restrict__ Bt, int ldb,
                                                 float* __restrict__ C, int ldc,
                                                 const float* __restrict__ bias,
                                                 int K, int accum) {
  __shared__ __align__(16) ushort_t As[128][40];
  __shared__ __align__(16) ushort_t Bs[128][40];
  int tid = threadIdx.x;
  int wave = tid >> 6, lane = tid & 63;
  int q = lane >> 4, l15 = lane & 15;
  int wr = wave >> 1, wc = wave & 1;
  int m0 = blockIdx.x * 128, n0 = blockIdx.y * 128;
  f32x4 acc[4][4] = {};
  int r = tid >> 1, sh = (tid & 1) * 16;
  const ushort_t* aSrc = A + (size_t)(m0 + r) * lda + sh;
  const ushort_t* bSrc = Bt + (size_t)(n0 + r) * ldb + sh;
  for (int k0 = 0; k0 < K; k0 += 32) {
    *(short8*)&As[r][sh]     = *(const short8*)(aSrc + k0);
    *(short8*)&As[r][sh + 8] = *(const short8*)(aSrc + k0 + 8);
    *(short8*)&Bs[r][sh]     = *(const short8*)(bSrc + k0);
    *(short8*)&Bs[r][sh + 8] = *(const short8*)(bSrc + k0 + 8);
    __syncthreads();
    frag8 af[4], bf[4];
#pragma unroll
    for (int i = 0; i < 4; i++) {
      af[i].s = *(const short8*)&As[wr * 64 + i * 16 + l15][q * 8];
      bf[i].s = *(const short8*)&Bs[wc * 64 + i * 16 + l15][q * 8];
    }
#pragma unroll
    for (int at = 0; at < 4; at++)
#pragma unroll
      for (int bt = 0; bt < 4; bt++)
        acc[at][bt] = __builtin_amdgcn_mfma_f32_16x16x32_bf16(af[at].b, bf[bt].b, acc[at][bt], 0, 0, 0);
    __syncthreads();
  }
#pragma unroll
  for (int at = 0; at < 4; at++)
#pragma unroll
    for (int bt = 0; bt < 4; bt++) {
      int mb = m0 + wr * 64 + at * 16 + q * 4;
      int n  = n0 + wc * 64 + bt * 16 + l15;
      float bv = bias ? bias[n] : 0.f;
#pragma unroll
      for (int i = 0; i < 4; i++) {
        size_t idx = (size_t)(mb + i) * ldc + n;
        float v = acc[at][bt][i] + bv;
        if (accum) v += C[idx];
        C[idx] = v;
      }
    }
}

// ---------------- GRU recurrence v7: lean sync protocol ----------------
// Partition as v6 (64 blocks = 16 rg x 4 cg, 128KB LDS weight slice). v6
// post-mortem: 4.34us/step is sync-overhead (4 block barriers + 2048 4B
// atomics). v7 protocol, 2 barriers/step:
//   prefetch C0 -> per-wave spin (tid0 on IC flag -> LDS `go`; other wave
//   leaders poll `go`) -> pull 768x8B atomics (1/thread) -> BARRIER ->
//   MFMA + G write -> BARRIER -> combine -> publish 256x8B from registers
//   (shfl-packed) -> vmcnt(0) -> LDS arrival counter; LAST wave does the
//   single IC flag add.
// Ordering audit: pull(t+1) vs MFMA-reads(t): post-G barrier. own-h write vs
// next MFMA read: post-pull barrier. publish->flag: vmcnt + lcnt chain.
// flag->pull: spin control dep. go/lcnt monotone, init'd pre-loop.
__global__ __launch_bounds__(1024) void gru_cols_k(
    const ushort_t* __restrict__ Wct,
    const float* __restrict__ C0,
    const float* __restrict__ INN,
    ull_t* __restrict__ hG,           // [2][256][64] u64 (4x bf16)
    unsigned* __restrict__ flags,     // [16] spaced 32 u32
    float* __restrict__ outF) {
  __shared__ __align__(16) ushort_t Wb[256][264];   // weight slice (135.2KB)
  __shared__ __align__(16) ushort_t h_lds[16][264]; // h(t), full 256 k (8.4KB)
  __shared__ float G[4][16][66];                    // gate pre-acts (16.9KB)
  __shared__ unsigned go, lcnt;

  const int tid = threadIdx.x;
  const int w = tid >> 6, lane = tid & 63;
  const int q = lane >> 4, l15 = lane & 15;
  const int rg = blockIdx.x & 15, cg = blockIdx.x >> 4;
  const int r0 = rg * 16;
  const int g = w >> 2, j = w & 3;

  unsigned* flag = flags + rg * 32;

  if (tid == 0) { go = 0u; lcnt = 0u; }
  // zero h(0) incl. pad
  for (int d = tid; d < 16 * 264 / 2; d += 1024) ((unsigned*)h_lds)[d] = 0u;
  // stage weight slice: Wb[g*64+lc][k] = Wct[g*256 + cg*64 + lc][k]
  for (int i = tid; i < 256 * 32; i += 1024) {
    int rr = i >> 5, ss = i & 31;
    int srow = (rr >> 6) * 256 + cg * 64 + (rr & 63);
    *(short8*)&Wb[rr][ss * 8] = *(const short8*)(Wct + (size_t)srow * 256 + ss * 8);
  }
  __syncthreads();

  const int crow = w;               // combine row == wave (64 thr per row)
  const int ccol = lane;            // combine local col 0..63
  const int hg = cg * 64 + ccol;    // global h-col

  for (int t = 0; t < T_; t++) {
    // prefetch C0/INN (independent of h -> in flight during spin)
    const float* c0t  = C0  + ((size_t)t * B_ + r0) * 1024;
    const float* innt = INN + ((size_t)t * B_ + r0) * 256;
    float c0he = c0t[(size_t)crow * 1024 + hg];
    float c0r  = c0t[(size_t)crow * 1024 + 256 + hg];
    float c0z  = c0t[(size_t)crow * 1024 + 512 + hg];
    float c0hn = c0t[(size_t)crow * 1024 + 768 + hg];
    float c0in = innt[(size_t)crow * 256 + hg];

    if (t > 0) {
      // per-wave gate: tid0 observes IC flag, broadcasts via LDS go
      if (w == 0) {
        if (lane == 0) {
          while (__hip_atomic_load(flag, __ATOMIC_ACQUIRE, __HIP_MEMORY_SCOPE_AGENT) < 4u * (unsigned)t)
            __builtin_amdgcn_s_sleep(2);
          __hip_atomic_store(&go, (unsigned)t, __ATOMIC_RELEASE, __HIP_MEMORY_SCOPE_WORKGROUP);
        }
      } else {
        if (lane == 0) {
          while (__hip_atomic_load(&go, __ATOMIC_ACQUIRE, __HIP_MEMORY_SCOPE_WORKGROUP) < (unsigned)t)
            __builtin_amdgcn_s_sleep(1);
        }
      }
      // wave reconverged -> pull the 3 remote slices (one 8B atomic per thread)
      if (tid < 768) {
        int s = tid >> 8;                       // 0..2
        int cgs = s + (s >= cg ? 1 : 0);
        int rem = tid & 255;
        int row = rem >> 4, cp = rem & 15;
        ull_t v = __hip_atomic_load(&hG[(size_t)(t & 1) * 256 * 64 + (size_t)(r0 + row) * 64 + cgs * 16 + cp],
                                    __ATOMIC_RELAXED, __HIP_MEMORY_SCOPE_AGENT);
        *(ull_t*)&h_lds[row][cgs * 64 + cp * 4] = v;
      }
      __syncthreads();   // BARRIER 1: all pulls + own h writes visible
    }

    // MFMA: wave (g,j) computes gate g, cols [16j,16j+16), rows 16, k=256
    f32x4 acc = {};
#pragma unroll
    for (int kc = 0; kc < 8; kc++) {
      frag8 a, b;
      a.s = *(const short8*)&h_lds[l15][kc * 32 + q * 8];
      b.s = *(const short8*)&Wb[g * 64 + j * 16 + l15][kc * 32 + q * 8];
      acc = __builtin_amdgcn_mfma_f32_16x16x32_bf16(a.b, b.b, acc, 0, 0, 0);
    }
#pragma unroll
    for (int i = 0; i < 4; i++) G[g][q * 4 + i][j * 16 + l15] = acc[i];
    __syncthreads();     // BARRIER 2: G complete; also orders MFMA reads vs next pull

    // combine: thread (crow, ccol) mixes the 4 gates for its h element
    float henc = G[0][crow][ccol] + c0he;
    float rp   = G[1][crow][ccol] + c0r;
    float zp   = G[2][crow][ccol] + c0z;
    float hn   = G[3][crow][ccol] + c0hn;
    float rgate = 1.f / (1.f + expf(-rp));
    float zgate = 1.f / (1.f + expf(-zp));
    float ng = tanhf(c0in + rgate * hn);
    float hv = (1.f - zgate) * ng + zgate * henc;

    if (t < T_ - 1) {
      // own slice to LDS for next step (ordered by next BARRIER 1)
      unsigned hvb = (unsigned)f2bf(hv);
      h_lds[crow][cg * 64 + ccol] = (ushort_t)hvb;
      // publish from registers: shfl-pack 4 cols -> one 8B agent atomic
      unsigned p1 = (unsigned)__shfl_xor((int)hvb, 1);
      unsigned v32 = hvb | (p1 << 16);          // valid on even lanes (cols 2c,2c+1)
      unsigned p2 = (unsigned)__shfl_xor((int)v32, 2);
      if ((lane & 3) == 0) {
        ull_t v64 = (ull_t)v32 | ((ull_t)p2 << 32);   // cols 4c..4c+3
        __hip_atomic_store(&hG[(size_t)((t + 1) & 1) * 256 * 64 + (size_t)(r0 + crow) * 64 + cg * 16 + (lane >> 2)],
                           v64, __ATOMIC_RELAXED, __HIP_MEMORY_SCOPE_AGENT);
      }
      // wave-level completion -> LDS arrival counter -> last wave does IC flag add
      asm volatile("s_waitcnt vmcnt(0)" ::: "memory");
      if (lane == 0) {
        unsigned old = __hip_atomic_fetch_add(&lcnt, 1u, __ATOMIC_ACQ_REL, __HIP_MEMORY_SCOPE_WORKGROUP);
        if (old == 16u * (unsigned)t + 15u)
          __hip_atomic_fetch_add(flag, 1u, __ATOMIC_RELEASE, __HIP_MEMORY_SCOPE_AGENT);
      }
    } else {
      outF[(size_t)(r0 + crow) * 256 + hg] = hv;
    }
  }
}

// ---------------- launch ----------------
extern "C" void kernel_launch(void* const* d_in, const int* in_sizes, int n_in,
                              void* d_out, int out_size, void* d_ws, size_t ws_size,
                              hipStream_t stream) {
  const float* obs     = (const float*)d_in[0];
  const float* actions = (const float*)d_in[1];
  const float* W1  = (const float*)d_in[2];
  const float* b1  = (const float*)d_in[3];
  const float* g1  = (const float*)d_in[4];
  const float* be1 = (const float*)d_in[5];
  const float* W2  = (const float*)d_in[6];
  const float* b2  = (const float*)d_in[7];
  const float* g2  = (const float*)d_in[8];
  const float* be2 = (const float*)d_in[9];
  const float* W3  = (const float*)d_in[10];
  const float* b3  = (const float*)d_in[11];
  const float* Wih = (const float*)d_in[12];
  const float* bih = (const float*)d_in[13];
  const float* Whh = (const float*)d_in[14];
  const float* bhh = (const float*)d_in[15];
  const float* Whe = (const float*)d_in[16];
  const float* bhe = (const float*)d_in[17];
  const float* Wae = (const float*)d_in[18];
  const float* bae = (const float*)d_in[19];

  char* ws = (char*)d_ws;
  float*    C0    = (float*)(ws + OFF_C0);
  ushort_t* obsb  = (ushort_t*)(ws + OFF_OBSB);
  float*    Y     = (float*)(ws + OFF_Y);
  float*    Yg    = (float*)(ws + OFF_YG);
  ushort_t* XG    = (ushort_t*)(ws + OFF_XG);
  ushort_t* Pencb = (ushort_t*)(ws + OFF_PENCB);
  ushort_t* Xb    = (ushort_t*)(ws + OFF_XB);
  float*    INN   = (float*)(ws + OFF_INN);
  float*    AE    = (float*)(ws + OFF_AE);
  ushort_t* W1t   = (ushort_t*)(ws + OFF_W1T);
  ushort_t* W2t   = (ushort_t*)(ws + OFF_W2T);
  ushort_t* W3t   = (ushort_t*)(ws + OFF_W3T);
  ushort_t* Wiht  = (ushort_t*)(ws + OFF_WIHT);
  ushort_t* Whht  = (ushort_t*)(ws + OFF_WHHT);
  ushort_t* Wct   = (ushort_t*)(ws + OFF_WCT);
  float*    bsum  = (float*)(ws + OFF_BSUM);
  unsigned* flags = (unsigned*)(ws + OFF_FLAGS);
  ull_t*    hG    = (ull_t*)(ws + OFF_HG);
  float*    outF  = (float*)d_out;

  // prologue: casts / transposes / small precomputes
  cast_obs_k<<<MT_, 256, 0, stream>>>(obs, obsb);
  transpose_cast_k<<<dim3(16, 32), 256, 0, stream>>>(W1, W1t, 1024, 512);
  transpose_cast_k<<<dim3(16, 16), 256, 0, stream>>>(W2, W2t, 512, 512);
  transpose_cast_k<<<dim3(8, 16),  256, 0, stream>>>(W3, W3t, 512, 256);
  transpose_cast_k<<<dim3(24, 8),  256, 0, stream>>>(Wih, Wiht, 256, 768);
  transpose_cast_k<<<dim3(24, 8),  256, 0, stream>>>(Whh, Whht, 256, 768);
  wct_a_k<<<256, 256, 0, stream>>>(Whe, Wct);
  wct_b_k<<<768, 256, 0, stream>>>(Whe, Whh, Wct);
  bsum_k<<<3, 256, 0, stream>>>(bih, bhh, bsum);
  init_flags_k<<<1, 64, 0, stream>>>(flags);
  ae_k<<<MT_ * 16 / 256, 256, 0, stream>>>(actions, Wae, bae, AE);

  // MLP (parallel over all T*B rows, t-major) -- 128x128 tiles
  gemm_bt_k<<<dim3(256, 4), 256, 0, stream>>>(obsb, 1024, W1t, 1024, Y, 512, b1, 1024, 0);
  bn_elu_k<<<dim3(T_, 2), 256, 0, stream>>>(Y, g1, be1, Xb);
  gemm_bt_k<<<dim3(256, 4), 256, 0, stream>>>(Xb, 512, W2t, 512, Y, 512, b2, 512, 0);
  bn_elu_k<<<dim3(T_, 2), 256, 0, stream>>>(Y, g2, be2, Xb);
  gemm_bt_k<<<dim3(256, 2), 256, 0, stream>>>(Xb, 512, W3t, 512, Yg, 256, b3, 512, 0);
  cast_k<<<MT_ * 256 / 256, 256, 0, stream>>>(Yg, XG, (long)MT_ * 256);

  // per-step constants: Penc -> C0[:,0:256); r/z pre -> C0[:,256:768); hn0 -> C0[:,768:1024); INN
  penc_k<<<MT_, 256, 0, stream>>>(AE, Whe, bhe, C0, Pencb);
  gemm_bt_k<<<dim3(256, 4), 256, 0, stream>>>(XG, 256, Wiht, 256, C0 + 256, 1024, bsum, 256, 0);
  gemm_bt_k<<<dim3(256, 4), 256, 0, stream>>>(Pencb, 256, Whht, 256, C0 + 256, 1024, nullptr, 256, 1);
  gemm_bt_k<<<dim3(256, 2), 256, 0, stream>>>(Pencb, 256, Whht + 512 * 256, 256, C0 + 768, 1024, bhh + 512, 256, 0);
  gemm_bt_k<<<dim3(256, 2), 256, 0, stream>>>(XG, 256, Wiht + 512 * 256, 256, INN, 256, bih + 512, 256, 0);

  // recurrence: 64 blocks (16 rg x 4 cg), LDS-resident weight slices,
  // lean flag-synced h-exchange through the IC (no global barrier).
  gru_cols_k<<<64, 1024, 0, stream>>>(Wct, C0, INN, hG, flags, outF);
}

// Round 14
// 1114.756 us; speedup vs baseline: 1.1509x; 1.1509x over previous
//
#include <hip/hip_runtime.h>
#include <math.h>
#include <stdint.h>

// Problem constants
#define B_   256
#define T_   128
#define NIN_ 1024
#define H1_  512
#define E_   256
#define A_   16
#define MT_  (B_ * T_)   // 32768 rows, t-major: m = t*B_ + b

typedef unsigned short ushort_t;
typedef unsigned long long ull_t;
typedef __attribute__((ext_vector_type(8))) short   short8;
typedef __attribute__((ext_vector_type(8))) __bf16  bf16x8;
typedef __attribute__((ext_vector_type(4))) float   f32x4;

union frag8 { short8 s; bf16x8 b; };

__device__ __forceinline__ ushort_t f2bf(float f) {
  union { float f; unsigned u; } v; v.f = f;
  unsigned r = (v.u + 0x7FFFu + ((v.u >> 16) & 1u)) >> 16;   // RNE
  return (ushort_t)r;
}

// ---------------- workspace layout (bytes) ----------------
// C0 fp32 [T*B][1024] = 128MB at 0 (written late; obs_b bf16 64MB overlays it early)
// chunks of C0 row: [0:256)=Penc(h_enc init) [256:512)=r_pre0 [512:768)=z_pre0 [768:1024)=hn0
static constexpr size_t OFF_C0    = 0;
static constexpr size_t OFF_OBSB  = 0;                      // bf16 [32768][1024], dead after G1
static constexpr size_t OFF_Y     = 134217728;              // fp32 [32768][512] (Y1,Y2)
static constexpr size_t OFF_XGP   = 167772160;              // bf16 [32768][512] = [XG | Pencb]
static constexpr size_t OFF_XB    = 201326592;              // bf16 [32768][512] (X1,X2)
static constexpr size_t OFF_INN   = 201326592;              // fp32 [32768][256] (after XB dead)
static constexpr size_t OFF_AE    = 234881024;              // fp32 [32768][16]
static constexpr size_t OFF_W1T   = 236978176;              // bf16 [512][1024]
static constexpr size_t OFF_W2T   = 238026752;              // bf16 [512][512]
static constexpr size_t OFF_W3T   = 238551040;              // bf16 [256][512]
static constexpr size_t OFF_WC    = 239075328;              // bf16 [768][512] = [Wih^T | Whh^T]
static constexpr size_t OFF_WCT   = 240123904;              // bf16 [1024][256]  (combined W^T)
static constexpr size_t OFF_BSUM  = 241172480;              // fp32 [768]
static constexpr size_t OFF_FLAGS = 241176576;              // u32 [16] spaced 128B
static constexpr size_t OFF_HG    = 241238016;              // u64 [2][256][64] (bf16x4 h slices)

// ---------------- prologue kernels ----------------

// obs [B,T,NIN] fp32 -> obs_b bf16 t-major [t*B+b][NIN]
__global__ __launch_bounds__(256) void cast_obs_k(const float* __restrict__ obs,
                                                  ushort_t* __restrict__ out) {
  int row_in = blockIdx.x;              // b*T + t
  int b = row_in / T_, t = row_in - b * T_;
  const float4* s4 = (const float4*)(obs + (size_t)row_in * NIN_);
  float4 v = s4[threadIdx.x];
  ushort_t* d = out + (size_t)(t * B_ + b) * NIN_ + threadIdx.x * 4;
  d[0] = f2bf(v.x); d[1] = f2bf(v.y); d[2] = f2bf(v.z); d[3] = f2bf(v.w);
}

// generic fp32 [R,C] -> bf16 [C,R] transpose+cast, output row stride ldo
__global__ __launch_bounds__(256) void transpose_cast_k(const float* __restrict__ in,
                                                        ushort_t* __restrict__ out,
                                                        int R, int C, int ldo) {
  __shared__ float tile[32][33];
  int c0 = blockIdx.x * 32, r0 = blockIdx.y * 32;
  int tx = threadIdx.x & 31, ty = threadIdx.x >> 5;   // ty 0..7
  for (int i = 0; i < 4; i++) {
    int r = r0 + ty * 4 + i;
    if (r < R && (c0 + tx) < C) tile[ty * 4 + i][tx] = in[(size_t)r * C + c0 + tx];
  }
  __syncthreads();
  for (int i = 0; i < 4; i++) {
    int c = c0 + ty * 4 + i, r = r0 + tx;
    if (c < C && r < R) out[(size_t)c * ldo + r] = f2bf(tile[tx][ty * 4 + i]);
  }
}

// Wct rows 0..255: (Whe_h)^T  : Wct[c][k] = Whe[k][c]
__global__ __launch_bounds__(256) void wct_a_k(const float* __restrict__ Whe,
                                               ushort_t* __restrict__ Wct) {
  int c = blockIdx.x, k = threadIdx.x;
  Wct[(size_t)c * 256 + k] = f2bf(Whe[(size_t)k * 256 + c]);
}

// Wct rows 256..1023: (Whe_h @ Whh)^T computed in fp32, one bf16 rounding
__global__ __launch_bounds__(256) void wct_b_k(const float* __restrict__ Whe,
                                               const float* __restrict__ Whh,
                                               ushort_t* __restrict__ Wct) {
  int c = blockIdx.x;   // 0..767 (gh column)
  int k = threadIdx.x;  // h feature
  float acc = 0.f;
  for (int j = 0; j < 256; j++)
    acc += Whe[(size_t)k * 256 + j] * Whh[(size_t)j * 768 + c];
  Wct[(size_t)(256 + c) * 256 + k] = f2bf(acc);
}

__global__ void bsum_k(const float* __restrict__ bih, const float* __restrict__ bhh,
                       float* __restrict__ bs) {
  int i = blockIdx.x * 256 + threadIdx.x;
  if (i < 768) bs[i] = bih[i] + bhh[i];
}

__global__ void init_flags_k(unsigned* f) {
  if (threadIdx.x < 16) f[threadIdx.x * 32] = 0u;
}

// AE[m=t*B+b][k2] = actions[b,t,:] @ Wae + bae   (fp32)
__global__ __launch_bounds__(256) void ae_k(const float* __restrict__ actions,
                                            const float* __restrict__ Wae,
                                            const float* __restrict__ bae,
                                            float* __restrict__ AE) {
  int idx = blockIdx.x * 256 + threadIdx.x;
  int m = idx >> 4, k2 = idx & 15;
  int t = m >> 8, b = m & 255;
  const float* arow = actions + ((size_t)b * T_ + t) * A_;
  float acc = bae[k2];
  for (int k = 0; k < 16; k++) acc += arow[k] * Wae[k * 16 + k2];
  AE[(size_t)m * 16 + k2] = acc;
}

// Penc[t][b][j] = bhe[j] + (t>0 ? AE[t-1,b,:] @ Whe[256:272,:] : 0)
// writes fp32 into C0 cols [0:256) and bf16 copy into XGP cols [256:512)
__global__ __launch_bounds__(256) void penc_k(const float* __restrict__ AE,
                                              const float* __restrict__ Whe,
                                              const float* __restrict__ bhe,
                                              float* __restrict__ C0,
                                              ushort_t* __restrict__ XGP) {
  int m = blockIdx.x;          // t*B + b
  int j = threadIdx.x;         // 0..255
  __shared__ float a[16];
  if (threadIdx.x < 16)
    a[threadIdx.x] = (m >= B_) ? AE[(size_t)(m - B_) * 16 + threadIdx.x] : 0.f;
  __syncthreads();
  float acc = bhe[j];
  if (m >= B_) {
    for (int k = 0; k < 16; k++) acc += a[k] * Whe[(size_t)(256 + k) * 256 + j];
  }
  C0[(size_t)m * 1024 + j] = acc;
  XGP[(size_t)m * 512 + 256 + j] = f2bf(acc);
}

// per-t BatchNorm (training, biased var) + ELU, fp32 in -> bf16 out
// per-feature stats are column-independent -> split features across blockIdx.y
__global__ __launch_bounds__(256) void bn_elu_k(const float* __restrict__ Y,
                                                const float* __restrict__ g,
                                                const float* __restrict__ be,
                                                ushort_t* __restrict__ Xb) {
  int t = blockIdx.x, f = blockIdx.y * 256 + threadIdx.x;   // 512 features over 2 blocks
  const float* base = Y + (size_t)t * B_ * H1_;
  float s = 0.f, ss = 0.f;
  for (int b = 0; b < B_; b++) {
    float v = base[(size_t)b * H1_ + f];
    s += v; ss += v * v;
  }
  float mu  = s * (1.f / B_);
  float var = ss * (1.f / B_) - mu * mu;
  float inv = 1.f / sqrtf(var + 1e-5f);
  float sc = g[f] * inv, sh = be[f] - mu * sc;
  ushort_t* ob = Xb + (size_t)t * B_ * H1_;
  for (int b = 0; b < B_; b++) {
    float v = base[(size_t)b * H1_ + f] * sc + sh;
    float e = v > 0.f ? v : (expf(v) - 1.f);
    ob[(size_t)b * H1_ + f] = f2bf(e);
  }
}

// ---------------- bf16 MFMA GEMM: out[m,n] (+)= A[m,:] . Bt[n,:] + bias[n] ----------------
// 128x128 tile, BK=32, 256 threads (4 waves in 2x2, each 64x64, 4x4 frag grid).
// If Cb != nullptr: write bf16 to Cb (ldc), else fp32 to C (accum optional).
__global__ __launch_bounds__(256) void gemm_bt_k(const ushort_t* __restrict__ A, int lda,
                                                 const ushort_t* __restrict__ Bt, int ldb,
                                                 float* __restrict__ C,
                                                 ushort_t* __restrict__ Cb, int ldc,
                                                 const float* __restrict__ bias,
                                                 int K, int accum) {
  __shared__ __align__(16) ushort_t As[128][40];
  __shared__ __align__(16) ushort_t Bs[128][40];
  int tid = threadIdx.x;
  int wave = tid >> 6, lane = tid & 63;
  int q = lane >> 4, l15 = lane & 15;
  int wr = wave >> 1, wc = wave & 1;
  int m0 = blockIdx.x * 128, n0 = blockIdx.y * 128;
  f32x4 acc[4][4] = {};
  int r = tid >> 1, sh = (tid & 1) * 16;
  const ushort_t* aSrc = A + (size_t)(m0 + r) * lda + sh;
  const ushort_t* bSrc = Bt + (size_t)(n0 + r) * ldb + sh;
  for (int k0 = 0; k0 < K; k0 += 32) {
    *(short8*)&As[r][sh]     = *(const short8*)(aSrc + k0);
    *(short8*)&As[r][sh + 8] = *(const short8*)(aSrc + k0 + 8);
    *(short8*)&Bs[r][sh]     = *(const short8*)(bSrc + k0);
    *(short8*)&Bs[r][sh + 8] = *(const short8*)(bSrc + k0 + 8);
    __syncthreads();
    frag8 af[4], bf[4];
#pragma unroll
    for (int i = 0; i < 4; i++) {
      af[i].s = *(const short8*)&As[wr * 64 + i * 16 + l15][q * 8];
      bf[i].s = *(const short8*)&Bs[wc * 64 + i * 16 + l15][q * 8];
    }
#pragma unroll
    for (int at = 0; at < 4; at++)
#pragma unroll
      for (int bt = 0; bt < 4; bt++)
        acc[at][bt] = __builtin_amdgcn_mfma_f32_16x16x32_bf16(af[at].b, bf[bt].b, acc[at][bt], 0, 0, 0);
    __syncthreads();
  }
#pragma unroll
  for (int at = 0; at < 4; at++)
#pragma unroll
    for (int bt = 0; bt < 4; bt++) {
      int mb = m0 + wr * 64 + at * 16 + q * 4;
      int n  = n0 + wc * 64 + bt * 16 + l15;
      float bv = bias ? bias[n] : 0.f;
#pragma unroll
      for (int i = 0; i < 4; i++) {
        size_t idx = (size_t)(mb + i) * ldc + n;
        float v = acc[at][bt][i] + bv;
        if (Cb) {
          Cb[idx] = f2bf(v);
        } else {
          if (accum) v += C[idx];
          C[idx] = v;
        }
      }
    }
}

// ---------------- GRU recurrence v8: v6 protocol + 8B atomics ----------------
// Partition: 64 blocks = 16 rg x 4 cg. Block (rg,cg) owns batch rows
// [16rg,16rg+16) and h-cols [64cg,64cg+64); weight slice (128KB) LDS-resident.
// v7 post-mortem: hand-rolled per-wave spin + arrival counter REGRESSED
// (555->648); the hardware barrier release is cheaper. Revert to the proven v6
// protocol (tid0 IC spin + 4 __syncthreads) with ONE strict-subset change:
// 8B atomics halve the op count (pull 1536->768, publish 512->256).
__global__ __launch_bounds__(1024) void gru_cols_k(
    const ushort_t* __restrict__ Wct,
    const float* __restrict__ C0,
    const float* __restrict__ INN,
    ull_t* __restrict__ hG,           // [2][256][64] u64 (4x bf16)
    unsigned* __restrict__ flags,     // [16] spaced 32 u32
    float* __restrict__ outF) {
  __shared__ __align__(16) ushort_t Wb[256][264];   // weight slice (135.2KB)
  __shared__ __align__(16) ushort_t h_lds[16][264]; // h(t), full 256 k (8.4KB)
  __shared__ float G[4][16][66];                    // gate pre-acts (16.9KB)

  const int tid = threadIdx.x;
  const int w = tid >> 6, lane = tid & 63;
  const int q = lane >> 4, l15 = lane & 15;
  const int rg = blockIdx.x & 15, cg = blockIdx.x >> 4;
  const int r0 = rg * 16;
  const int g = w >> 2, j = w & 3;

  unsigned* flag = flags + rg * 32;

  // zero h(0) incl. pad
  for (int d = tid; d < 16 * 264 / 2; d += 1024) ((unsigned*)h_lds)[d] = 0u;
  // stage weight slice: Wb[g*64+lc][k] = Wct[g*256 + cg*64 + lc][k]
  for (int i = tid; i < 256 * 32; i += 1024) {
    int rr = i >> 5, ss = i & 31;
    int srow = (rr >> 6) * 256 + cg * 64 + (rr & 63);
    *(short8*)&Wb[rr][ss * 8] = *(const short8*)(Wct + (size_t)srow * 256 + ss * 8);
  }
  __syncthreads();

  const int crow = w;               // combine row == wave (64 thr per row)
  const int ccol = lane;            // combine local col 0..63
  const int hg = cg * 64 + ccol;    // global h-col

  for (int t = 0; t < T_; t++) {
    // prefetch C0/INN for combine (independent of h -> in flight during spin)
    const float* c0t  = C0  + ((size_t)t * B_ + r0) * 1024;
    const float* innt = INN + ((size_t)t * B_ + r0) * 256;
    float c0he = c0t[(size_t)crow * 1024 + hg];
    float c0r  = c0t[(size_t)crow * 1024 + 256 + hg];
    float c0z  = c0t[(size_t)crow * 1024 + 512 + hg];
    float c0hn = c0t[(size_t)crow * 1024 + 768 + hg];
    float c0in = innt[(size_t)crow * 256 + hg];

    if (t > 0) {
      // wait for all 4 cg-blocks of this rg to have published h(t)
      if (tid == 0) {
        unsigned target = 4u * (unsigned)t;
        while (__hip_atomic_load(flag, __ATOMIC_ACQUIRE, __HIP_MEMORY_SCOPE_AGENT) < target)
          __builtin_amdgcn_s_sleep(1);
      }
      __syncthreads();
      // pull the 3 remote slices (one 8B agent atomic per thread)
      if (tid < 768) {
        int s = tid >> 8;                       // 0..2
        int cgs = s + (s >= cg ? 1 : 0);
        int rem = tid & 255;
        int row = rem >> 4, cp = rem & 15;
        ull_t v = __hip_atomic_load(&hG[(size_t)(t & 1) * 256 * 64 + (size_t)(r0 + row) * 64 + cgs * 16 + cp],
                                    __ATOMIC_RELAXED, __HIP_MEMORY_SCOPE_AGENT);
        *(ull_t*)&h_lds[row][cgs * 64 + cp * 4] = v;
      }
      __syncthreads();
    }

    // MFMA: wave (g,j) computes gate g, cols [16j,16j+16), rows 16, k=256
    f32x4 acc = {};
#pragma unroll
    for (int kc = 0; kc < 8; kc++) {
      frag8 a, b;
      a.s = *(const short8*)&h_lds[l15][kc * 32 + q * 8];
      b.s = *(const short8*)&Wb[g * 64 + j * 16 + l15][kc * 32 + q * 8];
      acc = __builtin_amdgcn_mfma_f32_16x16x32_bf16(a.b, b.b, acc, 0, 0, 0);
    }
#pragma unroll
    for (int i = 0; i < 4; i++) G[g][q * 4 + i][j * 16 + l15] = acc[i];
    __syncthreads();

    // combine: thread (crow, ccol) mixes the 4 gates for its h element
    float henc = G[0][crow][ccol] + c0he;
    float rp   = G[1][crow][ccol] + c0r;
    float zp   = G[2][crow][ccol] + c0z;
    float hn   = G[3][crow][ccol] + c0hn;
    float rgate = 1.f / (1.f + expf(-rp));
    float zgate = 1.f / (1.f + expf(-zp));
    float ng = tanhf(c0in + rgate * hn);
    float hv = (1.f - zgate) * ng + zgate * henc;

    if (t < T_ - 1) {
      h_lds[crow][cg * 64 + ccol] = f2bf(hv);   // own slice, local
      __syncthreads();
      // publish own slice as 8B agent atomics (from LDS)
      if (tid < 256) {
        int row2 = tid >> 4, cp = tid & 15;
        ull_t v = *(const ull_t*)&h_lds[row2][cg * 64 + cp * 4];
        __hip_atomic_store(&hG[(size_t)((t + 1) & 1) * 256 * 64 + (size_t)(r0 + row2) * 64 + cg * 16 + cp],
                           v, __ATOMIC_RELAXED, __HIP_MEMORY_SCOPE_AGENT);
      }
      __syncthreads();                          // drains vmcnt -> stores done
      if (tid == 0)
        __hip_atomic_fetch_add(flag, 1u, __ATOMIC_RELEASE, __HIP_MEMORY_SCOPE_AGENT);
    } else {
      outF[(size_t)(r0 + crow) * 256 + hg] = hv;
    }
  }
}

// ---------------- launch ----------------
extern "C" void kernel_launch(void* const* d_in, const int* in_sizes, int n_in,
                              void* d_out, int out_size, void* d_ws, size_t ws_size,
                              hipStream_t stream) {
  const float* obs     = (const float*)d_in[0];
  const float* actions = (const float*)d_in[1];
  const float* W1  = (const float*)d_in[2];
  const float* b1  = (const float*)d_in[3];
  const float* g1  = (const float*)d_in[4];
  const float* be1 = (const float*)d_in[5];
  const float* W2  = (const float*)d_in[6];
  const float* b2  = (const float*)d_in[7];
  const float* g2  = (const float*)d_in[8];
  const float* be2 = (const float*)d_in[9];
  const float* W3  = (const float*)d_in[10];
  const float* b3  = (const float*)d_in[11];
  const float* Wih = (const float*)d_in[12];
  const float* bih = (const float*)d_in[13];
  const float* Whh = (const float*)d_in[14];
  const float* bhh = (const float*)d_in[15];
  const float* Whe = (const float*)d_in[16];
  const float* bhe = (const float*)d_in[17];
  const float* Wae = (const float*)d_in[18];
  const float* bae = (const float*)d_in[19];

  char* ws = (char*)d_ws;
  float*    C0    = (float*)(ws + OFF_C0);
  ushort_t* obsb  = (ushort_t*)(ws + OFF_OBSB);
  float*    Y     = (float*)(ws + OFF_Y);
  ushort_t* XGP   = (ushort_t*)(ws + OFF_XGP);
  ushort_t* Xb    = (ushort_t*)(ws + OFF_XB);
  float*    INN   = (float*)(ws + OFF_INN);
  float*    AE    = (float*)(ws + OFF_AE);
  ushort_t* W1t   = (ushort_t*)(ws + OFF_W1T);
  ushort_t* W2t   = (ushort_t*)(ws + OFF_W2T);
  ushort_t* W3t   = (ushort_t*)(ws + OFF_W3T);
  ushort_t* WC    = (ushort_t*)(ws + OFF_WC);
  ushort_t* Wct   = (ushort_t*)(ws + OFF_WCT);
  float*    bsum  = (float*)(ws + OFF_BSUM);
  unsigned* flags = (unsigned*)(ws + OFF_FLAGS);
  ull_t*    hG    = (ull_t*)(ws + OFF_HG);
  float*    outF  = (float*)d_out;

  // prologue: casts / transposes / small precomputes
  cast_obs_k<<<MT_, 256, 0, stream>>>(obs, obsb);
  transpose_cast_k<<<dim3(16, 32), 256, 0, stream>>>(W1, W1t, 1024, 512, 1024);
  transpose_cast_k<<<dim3(16, 16), 256, 0, stream>>>(W2, W2t, 512, 512, 512);
  transpose_cast_k<<<dim3(8, 16),  256, 0, stream>>>(W3, W3t, 512, 256, 512);
  transpose_cast_k<<<dim3(24, 8),  256, 0, stream>>>(Wih, WC, 256, 768, 512);
  transpose_cast_k<<<dim3(24, 8),  256, 0, stream>>>(Whh, WC + 256, 256, 768, 512);
  wct_a_k<<<256, 256, 0, stream>>>(Whe, Wct);
  wct_b_k<<<768, 256, 0, stream>>>(Whe, Whh, Wct);
  bsum_k<<<3, 256, 0, stream>>>(bih, bhh, bsum);
  init_flags_k<<<1, 64, 0, stream>>>(flags);
  ae_k<<<MT_ * 16 / 256, 256, 0, stream>>>(actions, Wae, bae, AE);

  // MLP (parallel over all T*B rows, t-major) -- 128x128 tiles
  gemm_bt_k<<<dim3(256, 4), 256, 0, stream>>>(obsb, 1024, W1t, 1024, Y, nullptr, 512, b1, 1024, 0);
  bn_elu_k<<<dim3(T_, 2), 256, 0, stream>>>(Y, g1, be1, Xb);
  gemm_bt_k<<<dim3(256, 4), 256, 0, stream>>>(Xb, 512, W2t, 512, Y, nullptr, 512, b2, 512, 0);
  bn_elu_k<<<dim3(T_, 2), 256, 0, stream>>>(Y, g2, be2, Xb);
  // G3 writes bf16 XG directly into XGP cols [0:256)
  gemm_bt_k<<<dim3(256, 2), 256, 0, stream>>>(Xb, 512, W3t, 512, nullptr, XGP, 512, b3, 512, 0);

  // per-step constants: Penc -> C0[:,0:256) + XGP[:,256:512); then
  // ONE K=512 GEMM for r/z pre (gih+ghh merged); hn0; INN
  penc_k<<<MT_, 256, 0, stream>>>(AE, Whe, bhe, C0, XGP);
  gemm_bt_k<<<dim3(256, 4), 256, 0, stream>>>(XGP, 512, WC, 512, C0 + 256, nullptr, 1024, bsum, 512, 0);
  gemm_bt_k<<<dim3(256, 2), 256, 0, stream>>>(XGP + 256, 512, WC + 512 * 512 + 256, 512, C0 + 768, nullptr, 1024, bhh + 512, 256, 0);
  gemm_bt_k<<<dim3(256, 2), 256, 0, stream>>>(XGP, 512, WC + 512 * 512, 512, INN, nullptr, 256, bih + 512, 256, 0);

  // recurrence: 64 blocks (16 rg x 4 cg), LDS-resident weight slices,
  // v6 flag-synced h-exchange through the IC (no global barrier), 8B atomics.
  gru_cols_k<<<64, 1024, 0, stream>>>(Wct, C0, INN, hG, flags, outF);
}

// Round 17
// 1090.742 us; speedup vs baseline: 1.1762x; 1.0220x over previous
//
#include <hip/hip_runtime.h>
#include <math.h>
#include <stdint.h>

// Problem constants
#define B_   256
#define T_   128
#define NIN_ 1024
#define H1_  512
#define E_   256
#define A_   16
#define MT_  (B_ * T_)   // 32768 rows, t-major: m = t*B_ + b

typedef unsigned short ushort_t;
typedef unsigned long long ull_t;
typedef __attribute__((ext_vector_type(8))) short   short8;
typedef __attribute__((ext_vector_type(8))) __bf16  bf16x8;
typedef __attribute__((ext_vector_type(4))) float   f32x4;

union frag8 { short8 s; bf16x8 b; };

__device__ __forceinline__ ushort_t f2bf(float f) {
  union { float f; unsigned u; } v; v.f = f;
  unsigned r = (v.u + 0x7FFFu + ((v.u >> 16) & 1u)) >> 16;   // RNE
  return (ushort_t)r;
}

// async global->LDS, 16B per lane; LDS dest = wave-uniform base + lane*16
__device__ __forceinline__ void gl_lds16(const ushort_t* g, ushort_t* l) {
  __builtin_amdgcn_global_load_lds((const __attribute__((address_space(1))) void*)g,
                                   (__attribute__((address_space(3))) void*)l, 16, 0, 0);
}

// ---------------- workspace layout (bytes) ----------------
// C0 fp32 [T*B][1024] = 128MB at 0 (written late; obs_b bf16 64MB overlays it early)
// chunks of C0 row: [0:256)=Penc(h_enc init) [256:512)=r_pre0 [512:768)=z_pre0 [768:1024)=hn0
static constexpr size_t OFF_C0    = 0;
static constexpr size_t OFF_OBSB  = 0;                      // bf16 [32768][1024], dead after G1
static constexpr size_t OFF_Y     = 134217728;              // fp32 [32768][512] (Y1,Y2)
static constexpr size_t OFF_XGP   = 167772160;              // bf16 [32768][512] = [XG | Pencb]
static constexpr size_t OFF_XB    = 201326592;              // bf16 [32768][512] (X1,X2)
static constexpr size_t OFF_INN   = 201326592;              // fp32 [32768][256] (after XB dead)
static constexpr size_t OFF_AE    = 234881024;              // fp32 [32768][16]
static constexpr size_t OFF_W1T   = 236978176;              // bf16 [512][1024]
static constexpr size_t OFF_W2T   = 238026752;              // bf16 [512][512]
static constexpr size_t OFF_W3T   = 238551040;              // bf16 [256][512]
static constexpr size_t OFF_WC    = 239075328;              // bf16 [768][512] = [Wih^T | Whh^T]
static constexpr size_t OFF_WCT   = 240123904;              // bf16 [1024][256]  (combined W^T)
static constexpr size_t OFF_BSUM  = 241172480;              // fp32 [768]
static constexpr size_t OFF_FLAGS = 241176576;              // u32 [16] spaced 128B
static constexpr size_t OFF_HG    = 241238016;              // u64 [2][256][64] (bf16x4 h slices)

// ---------------- prologue kernels ----------------

// obs [B,T,NIN] fp32 -> obs_b bf16 t-major [t*B+b][NIN]
__global__ __launch_bounds__(256) void cast_obs_k(const float* __restrict__ obs,
                                                  ushort_t* __restrict__ out) {
  int row_in = blockIdx.x;              // b*T + t
  int b = row_in / T_, t = row_in - b * T_;
  const float4* s4 = (const float4*)(obs + (size_t)row_in * NIN_);
  float4 v = s4[threadIdx.x];
  ushort_t* d = out + (size_t)(t * B_ + b) * NIN_ + threadIdx.x * 4;
  d[0] = f2bf(v.x); d[1] = f2bf(v.y); d[2] = f2bf(v.z); d[3] = f2bf(v.w);
}

// generic fp32 [R,C] -> bf16 [C,R] transpose+cast, output row stride ldo
__global__ __launch_bounds__(256) void transpose_cast_k(const float* __restrict__ in,
                                                        ushort_t* __restrict__ out,
                                                        int R, int C, int ldo) {
  __shared__ float tile[32][33];
  int c0 = blockIdx.x * 32, r0 = blockIdx.y * 32;
  int tx = threadIdx.x & 31, ty = threadIdx.x >> 5;   // ty 0..7
  for (int i = 0; i < 4; i++) {
    int r = r0 + ty * 4 + i;
    if (r < R && (c0 + tx) < C) tile[ty * 4 + i][tx] = in[(size_t)r * C + c0 + tx];
  }
  __syncthreads();
  for (int i = 0; i < 4; i++) {
    int c = c0 + ty * 4 + i, r = r0 + tx;
    if (c < C && r < R) out[(size_t)c * ldo + r] = f2bf(tile[tx][ty * 4 + i]);
  }
}

// Wct rows 0..255: (Whe_h)^T  : Wct[c][k] = Whe[k][c]
__global__ __launch_bounds__(256) void wct_a_k(const float* __restrict__ Whe,
                                               ushort_t* __restrict__ Wct) {
  int c = blockIdx.x, k = threadIdx.x;
  Wct[(size_t)c * 256 + k] = f2bf(Whe[(size_t)k * 256 + c]);
}

// Wct rows 256..1023: (Whe_h @ Whh)^T computed in fp32, one bf16 rounding
__global__ __launch_bounds__(256) void wct_b_k(const float* __restrict__ Whe,
                                               const float* __restrict__ Whh,
                                               ushort_t* __restrict__ Wct) {
  int c = blockIdx.x;   // 0..767 (gh column)
  int k = threadIdx.x;  // h feature
  float acc = 0.f;
  for (int j = 0; j < 256; j++)
    acc += Whe[(size_t)k * 256 + j] * Whh[(size_t)j * 768 + c];
  Wct[(size_t)(256 + c) * 256 + k] = f2bf(acc);
}

__global__ void bsum_k(const float* __restrict__ bih, const float* __restrict__ bhh,
                       float* __restrict__ bs) {
  int i = blockIdx.x * 256 + threadIdx.x;
  if (i < 768) bs[i] = bih[i] + bhh[i];
}

__global__ void init_flags_k(unsigned* f) {
  if (threadIdx.x < 16) f[threadIdx.x * 32] = 0u;
}

// AE[m=t*B+b][k2] = actions[b,t,:] @ Wae + bae   (fp32)
__global__ __launch_bounds__(256) void ae_k(const float* __restrict__ actions,
                                            const float* __restrict__ Wae,
                                            const float* __restrict__ bae,
                                            float* __restrict__ AE) {
  int idx = blockIdx.x * 256 + threadIdx.x;
  int m = idx >> 4, k2 = idx & 15;
  int t = m >> 8, b = m & 255;
  const float* arow = actions + ((size_t)b * T_ + t) * A_;
  float acc = bae[k2];
  for (int k = 0; k < 16; k++) acc += arow[k] * Wae[k * 16 + k2];
  AE[(size_t)m * 16 + k2] = acc;
}

// Penc[t][b][j] = bhe[j] + (t>0 ? AE[t-1,b,:] @ Whe[256:272,:] : 0)
// writes fp32 into C0 cols [0:256) and bf16 copy into XGP cols [256:512)
__global__ __launch_bounds__(256) void penc_k(const float* __restrict__ AE,
                                              const float* __restrict__ Whe,
                                              const float* __restrict__ bhe,
                                              float* __restrict__ C0,
                                              ushort_t* __restrict__ XGP) {
  int m = blockIdx.x;          // t*B + b
  int j = threadIdx.x;         // 0..255
  __shared__ float a[16];
  if (threadIdx.x < 16)
    a[threadIdx.x] = (m >= B_) ? AE[(size_t)(m - B_) * 16 + threadIdx.x] : 0.f;
  __syncthreads();
  float acc = bhe[j];
  if (m >= B_) {
    for (int k = 0; k < 16; k++) acc += a[k] * Whe[(size_t)(256 + k) * 256 + j];
  }
  C0[(size_t)m * 1024 + j] = acc;
  XGP[(size_t)m * 512 + 256 + j] = f2bf(acc);
}

// per-t BatchNorm (training, biased var) + ELU, fp32 in -> bf16 out
// per-feature stats are column-independent -> split features across blockIdx.y
__global__ __launch_bounds__(256) void bn_elu_k(const float* __restrict__ Y,
                                                const float* __restrict__ g,
                                                const float* __restrict__ be,
                                                ushort_t* __restrict__ Xb) {
  int t = blockIdx.x, f = blockIdx.y * 256 + threadIdx.x;   // 512 features over 2 blocks
  const float* base = Y + (size_t)t * B_ * H1_;
  float s = 0.f, ss = 0.f;
  for (int b = 0; b < B_; b++) {
    float v = base[(size_t)b * H1_ + f];
    s += v; ss += v * v;
  }
  float mu  = s * (1.f / B_);
  float var = ss * (1.f / B_) - mu * mu;
  float inv = 1.f / sqrtf(var + 1e-5f);
  float sc = g[f] * inv, sh = be[f] - mu * sc;
  ushort_t* ob = Xb + (size_t)t * B_ * H1_;
  for (int b = 0; b < B_; b++) {
    float v = base[(size_t)b * H1_ + f] * sc + sh;
    float e = v > 0.f ? v : (expf(v) - 1.f);
    ob[(size_t)b * H1_ + f] = f2bf(e);
  }
}

// ---------------- bf16 MFMA GEMM: out[m,n] (+)= A[m,:] . Bt[n,:] + bias[n] ----------------
// m97-style: 128x128 tile, BK=32, 256 threads (4 waves 2x2, each 64x64, 4x4 frags),
// LINEAR LDS [128][32] (64B rows) + global_load_lds width-16 (async DMA, no VGPR
// round-trip). Wave w stages rows [32w,32w+32) of A and B: 2 issues of 16 rows each;
// lane l -> row base+(l>>2), 16B seg l&3 (matches DMA's base+lane*16 layout).
// If Cb != nullptr: write bf16 to Cb (ldc), else fp32 to C (accum optional).
__global__ __launch_bounds__(256) void gemm_bt_k(const ushort_t* __restrict__ A, int lda,
                                                 const ushort_t* __restrict__ Bt, int ldb,
                                                 float* __restrict__ C,
                                                 ushort_t* __restrict__ Cb, int ldc,
                                                 const float* __restrict__ bias,
                                                 int K, int accum) {
  __shared__ __align__(16) ushort_t As[128 * 32];   // 8KB, linear: row*32 + col
  __shared__ __align__(16) ushort_t Bs[128 * 32];   // 8KB
  int tid = threadIdx.x;
  int wave = tid >> 6, lane = tid & 63;
  int q = lane >> 4, l15 = lane & 15;
  int wr = wave >> 1, wc = wave & 1;
  int m0 = blockIdx.x * 128, n0 = blockIdx.y * 128;
  f32x4 acc[4][4] = {};
  const int rbase = wave * 32;
  const int srow = lane >> 2, seg = lane & 3;
  const ushort_t* aS = A + (size_t)(m0 + rbase + srow) * lda + seg * 8;
  const ushort_t* bS = Bt + (size_t)(n0 + rbase + srow) * ldb + seg * 8;
  for (int k0 = 0; k0 < K; k0 += 32) {
    gl_lds16(aS + k0,                      &As[rbase * 32]);
    gl_lds16(aS + (size_t)16 * lda + k0,   &As[(rbase + 16) * 32]);
    gl_lds16(bS + k0,                      &Bs[rbase * 32]);
    gl_lds16(bS + (size_t)16 * ldb + k0,   &Bs[(rbase + 16) * 32]);
    __syncthreads();                       // drains vmcnt (DMA done) + barrier
    frag8 af[4], bf[4];
#pragma unroll
    for (int i = 0; i < 4; i++) {
      af[i].s = *(const short8*)&As[(wr * 64 + i * 16 + l15) * 32 + q * 8];
      bf[i].s = *(const short8*)&Bs[(wc * 64 + i * 16 + l15) * 32 + q * 8];
    }
#pragma unroll
    for (int at = 0; at < 4; at++)
#pragma unroll
      for (int bt = 0; bt < 4; bt++)
        acc[at][bt] = __builtin_amdgcn_mfma_f32_16x16x32_bf16(af[at].b, bf[bt].b, acc[at][bt], 0, 0, 0);
    __syncthreads();
  }
#pragma unroll
  for (int at = 0; at < 4; at++)
#pragma unroll
    for (int bt = 0; bt < 4; bt++) {
      int mb = m0 + wr * 64 + at * 16 + q * 4;
      int n  = n0 + wc * 64 + bt * 16 + l15;
      float bv = bias ? bias[n] : 0.f;
#pragma unroll
      for (int i = 0; i < 4; i++) {
        size_t idx = (size_t)(mb + i) * ldc + n;
        float v = acc[at][bt][i] + bv;
        if (Cb) {
          Cb[idx] = f2bf(v);
        } else {
          if (accum) v += C[idx];
          C[idx] = v;
        }
      }
    }
}

// ---------------- GRU recurrence v9: v8 + early own-kc MFMA ----------------
// Partition: 64 blocks = 16 rg x 4 cg; 128KB LDS weight slice; v6 sync protocol
// (tid0 IC spin + 4 __syncthreads) + 8B atomics (v8, measured 529us).
// v9 subset change: the 2 own-column kc sub-tiles (k in [64cg,64cg+64)) read
// h_lds cols written by OUR OWN combine last step (barrier'd) -> compute those
// 8 MFMAs BEFORE the spin/pull; only 6/8 kc remain on the post-pull path.
// Ordering: early MFMA reads own cols; pulls write remote cols only (disjoint);
// all barriers unchanged.
__global__ __launch_bounds__(1024) void gru_cols_k(
    const ushort_t* __restrict__ Wct,
    const float* __restrict__ C0,
    const float* __restrict__ INN,
    ull_t* __restrict__ hG,           // [2][256][64] u64 (4x bf16)
    unsigned* __restrict__ flags,     // [16] spaced 32 u32
    float* __restrict__ outF) {
  __shared__ __align__(16) ushort_t Wb[256][264];   // weight slice (135.2KB)
  __shared__ __align__(16) ushort_t h_lds[16][264]; // h(t), full 256 k (8.4KB)
  __shared__ float G[4][16][66];                    // gate pre-acts (16.9KB)

  const int tid = threadIdx.x;
  const int w = tid >> 6, lane = tid & 63;
  const int q = lane >> 4, l15 = lane & 15;
  const int rg = blockIdx.x & 15, cg = blockIdx.x >> 4;
  const int r0 = rg * 16;
  const int g = w >> 2, j = w & 3;

  unsigned* flag = flags + rg * 32;

  // zero h(0) incl. pad
  for (int d = tid; d < 16 * 264 / 2; d += 1024) ((unsigned*)h_lds)[d] = 0u;
  // stage weight slice: Wb[g*64+lc][k] = Wct[g*256 + cg*64 + lc][k]
  for (int i = tid; i < 256 * 32; i += 1024) {
    int rr = i >> 5, ss = i & 31;
    int srow = (rr >> 6) * 256 + cg * 64 + (rr & 63);
    *(short8*)&Wb[rr][ss * 8] = *(const short8*)(Wct + (size_t)srow * 256 + ss * 8);
  }
  __syncthreads();

  const int crow = w;               // combine row == wave (64 thr per row)
  const int ccol = lane;            // combine local col 0..63
  const int hg = cg * 64 + ccol;    // global h-col
  const int kcown = cg * 2;         // own-col kc range: {kcown, kcown+1}

  for (int t = 0; t < T_; t++) {
    // prefetch C0/INN for combine (independent of h -> in flight during spin)
    const float* c0t  = C0  + ((size_t)t * B_ + r0) * 1024;
    const float* innt = INN + ((size_t)t * B_ + r0) * 256;
    float c0he = c0t[(size_t)crow * 1024 + hg];
    float c0r  = c0t[(size_t)crow * 1024 + 256 + hg];
    float c0z  = c0t[(size_t)crow * 1024 + 512 + hg];
    float c0hn = c0t[(size_t)crow * 1024 + 768 + hg];
    float c0in = innt[(size_t)crow * 256 + hg];

    // early MFMA on own k-cols (valid since prev step's own write + barrier)
    f32x4 acc = {};
#pragma unroll
    for (int e = 0; e < 2; e++) {
      int kc = kcown + e;
      frag8 a, b;
      a.s = *(const short8*)&h_lds[l15][kc * 32 + q * 8];
      b.s = *(const short8*)&Wb[g * 64 + j * 16 + l15][kc * 32 + q * 8];
      acc = __builtin_amdgcn_mfma_f32_16x16x32_bf16(a.b, b.b, acc, 0, 0, 0);
    }

    if (t > 0) {
      // wait for all 4 cg-blocks of this rg to have published h(t)
      if (tid == 0) {
        unsigned target = 4u * (unsigned)t;
        while (__hip_atomic_load(flag, __ATOMIC_ACQUIRE, __HIP_MEMORY_SCOPE_AGENT) < target)
          __builtin_amdgcn_s_sleep(1);
      }
      __syncthreads();
      // pull the 3 remote slices (one 8B agent atomic per thread)
      if (tid < 768) {
        int s = tid >> 8;                       // 0..2
        int cgs = s + (s >= cg ? 1 : 0);
        int rem = tid & 255;
        int row = rem >> 4, cp = rem & 15;
        ull_t v = __hip_atomic_load(&hG[(size_t)(t & 1) * 256 * 64 + (size_t)(r0 + row) * 64 + cgs * 16 + cp],
                                    __ATOMIC_RELAXED, __HIP_MEMORY_SCOPE_AGENT);
        *(ull_t*)&h_lds[row][cgs * 64 + cp * 4] = v;
      }
      __syncthreads();
    }

    // remaining MFMA: the 6 remote kc sub-tiles
#pragma unroll
    for (int kc = 0; kc < 8; kc++) {
      if (kc == kcown || kc == kcown + 1) continue;   // wave-uniform branch
      frag8 a, b;
      a.s = *(const short8*)&h_lds[l15][kc * 32 + q * 8];
      b.s = *(const short8*)&Wb[g * 64 + j * 16 + l15][kc * 32 + q * 8];
      acc = __builtin_amdgcn_mfma_f32_16x16x32_bf16(a.b, b.b, acc, 0, 0, 0);
    }
#pragma unroll
    for (int i = 0; i < 4; i++) G[g][q * 4 + i][j * 16 + l15] = acc[i];
    __syncthreads();

    // combine: thread (crow, ccol) mixes the 4 gates for its h element
    float henc = G[0][crow][ccol] + c0he;
    float rp   = G[1][crow][ccol] + c0r;
    float zp   = G[2][crow][ccol] + c0z;
    float hn   = G[3][crow][ccol] + c0hn;
    float rgate = 1.f / (1.f + expf(-rp));
    float zgate = 1.f / (1.f + expf(-zp));
    float ng = tanhf(c0in + rgate * hn);
    float hv = (1.f - zgate) * ng + zgate * henc;

    if (t < T_ - 1) {
      h_lds[crow][cg * 64 + ccol] = f2bf(hv);   // own slice, local
      __syncthreads();
      // publish own slice as 8B agent atomics (from LDS)
      if (tid < 256) {
        int row2 = tid >> 4, cp = tid & 15;
        ull_t v = *(const ull_t*)&h_lds[row2][cg * 64 + cp * 4];
        __hip_atomic_store(&hG[(size_t)((t + 1) & 1) * 256 * 64 + (size_t)(r0 + row2) * 64 + cg * 16 + cp],
                           v, __ATOMIC_RELAXED, __HIP_MEMORY_SCOPE_AGENT);
      }
      __syncthreads();                          // drains vmcnt -> stores done
      if (tid == 0)
        __hip_atomic_fetch_add(flag, 1u, __ATOMIC_RELEASE, __HIP_MEMORY_SCOPE_AGENT);
    } else {
      outF[(size_t)(r0 + crow) * 256 + hg] = hv;
    }
  }
}

// ---------------- launch ----------------
extern "C" void kernel_launch(void* const* d_in, const int* in_sizes, int n_in,
                              void* d_out, int out_size, void* d_ws, size_t ws_size,
                              hipStream_t stream) {
  const float* obs     = (const float*)d_in[0];
  const float* actions = (const float*)d_in[1];
  const float* W1  = (const float*)d_in[2];
  const float* b1  = (const float*)d_in[3];
  const float* g1  = (const float*)d_in[4];
  const float* be1 = (const float*)d_in[5];
  const float* W2  = (const float*)d_in[6];
  const float* b2  = (const float*)d_in[7];
  const float* g2  = (const float*)d_in[8];
  const float* be2 = (const float*)d_in[9];
  const float* W3  = (const float*)d_in[10];
  const float* b3  = (const float*)d_in[11];
  const float* Wih = (const float*)d_in[12];
  const float* bih = (const float*)d_in[13];
  const float* Whh = (const float*)d_in[14];
  const float* bhh = (const float*)d_in[15];
  const float* Whe = (const float*)d_in[16];
  const float* bhe = (const float*)d_in[17];
  const float* Wae = (const float*)d_in[18];
  const float* bae = (const float*)d_in[19];

  char* ws = (char*)d_ws;
  float*    C0    = (float*)(ws + OFF_C0);
  ushort_t* obsb  = (ushort_t*)(ws + OFF_OBSB);
  float*    Y     = (float*)(ws + OFF_Y);
  ushort_t* XGP   = (ushort_t*)(ws + OFF_XGP);
  ushort_t* Xb    = (ushort_t*)(ws + OFF_XB);
  float*    INN   = (float*)(ws + OFF_INN);
  float*    AE    = (float*)(ws + OFF_AE);
  ushort_t* W1t   = (ushort_t*)(ws + OFF_W1T);
  ushort_t* W2t   = (ushort_t*)(ws + OFF_W2T);
  ushort_t* W3t   = (ushort_t*)(ws + OFF_W3T);
  ushort_t* WC    = (ushort_t*)(ws + OFF_WC);
  ushort_t* Wct   = (ushort_t*)(ws + OFF_WCT);
  float*    bsum  = (float*)(ws + OFF_BSUM);
  unsigned* flags = (unsigned*)(ws + OFF_FLAGS);
  ull_t*    hG    = (ull_t*)(ws + OFF_HG);
  float*    outF  = (float*)d_out;

  // prologue: casts / transposes / small precomputes
  cast_obs_k<<<MT_, 256, 0, stream>>>(obs, obsb);
  transpose_cast_k<<<dim3(16, 32), 256, 0, stream>>>(W1, W1t, 1024, 512, 1024);
  transpose_cast_k<<<dim3(16, 16), 256, 0, stream>>>(W2, W2t, 512, 512, 512);
  transpose_cast_k<<<dim3(8, 16),  256, 0, stream>>>(W3, W3t, 512, 256, 512);
  transpose_cast_k<<<dim3(24, 8),  256, 0, stream>>>(Wih, WC, 256, 768, 512);
  transpose_cast_k<<<dim3(24, 8),  256, 0, stream>>>(Whh, WC + 256, 256, 768, 512);
  wct_a_k<<<256, 256, 0, stream>>>(Whe, Wct);
  wct_b_k<<<768, 256, 0, stream>>>(Whe, Whh, Wct);
  bsum_k<<<3, 256, 0, stream>>>(bih, bhh, bsum);
  init_flags_k<<<1, 64, 0, stream>>>(flags);
  ae_k<<<MT_ * 16 / 256, 256, 0, stream>>>(actions, Wae, bae, AE);

  // MLP (parallel over all T*B rows, t-major) -- 128x128 tiles, m97 staging
  gemm_bt_k<<<dim3(256, 4), 256, 0, stream>>>(obsb, 1024, W1t, 1024, Y, nullptr, 512, b1, 1024, 0);
  bn_elu_k<<<dim3(T_, 2), 256, 0, stream>>>(Y, g1, be1, Xb);
  gemm_bt_k<<<dim3(256, 4), 256, 0, stream>>>(Xb, 512, W2t, 512, Y, nullptr, 512, b2, 512, 0);
  bn_elu_k<<<dim3(T_, 2), 256, 0, stream>>>(Y, g2, be2, Xb);
  // G3 writes bf16 XG directly into XGP cols [0:256)
  gemm_bt_k<<<dim3(256, 2), 256, 0, stream>>>(Xb, 512, W3t, 512, nullptr, XGP, 512, b3, 512, 0);

  // per-step constants: Penc -> C0[:,0:256) + XGP[:,256:512); then
  // ONE K=512 GEMM for r/z pre (gih+ghh merged); hn0; INN
  penc_k<<<MT_, 256, 0, stream>>>(AE, Whe, bhe, C0, XGP);
  gemm_bt_k<<<dim3(256, 4), 256, 0, stream>>>(XGP, 512, WC, 512, C0 + 256, nullptr, 1024, bsum, 512, 0);
  gemm_bt_k<<<dim3(256, 2), 256, 0, stream>>>(XGP + 256, 512, WC + 512 * 512 + 256, 512, C0 + 768, nullptr, 1024, bhh + 512, 256, 0);
  gemm_bt_k<<<dim3(256, 2), 256, 0, stream>>>(XGP, 512, WC + 512 * 512, 512, INN, nullptr, 256, bih + 512, 256, 0);

  // recurrence: 64 blocks (16 rg x 4 cg), LDS-resident weight slices,
  // v6 flag-synced h-exchange through the IC, 8B atomics, early own-kc MFMA.
  gru_cols_k<<<64, 1024, 0, stream>>>(Wct, C0, INN, hG, flags, outF);
}